// Round 10
// baseline (1125.493 us; speedup 1.0000x reference)
//
#include <hip/hip_runtime.h>
#include <hip/hip_bf16.h>
#include <cstdint>
#include <cstddef>

typedef __bf16 bf16_t;
typedef __bf16 bf16x4 __attribute__((ext_vector_type(4)));
typedef __bf16 bf16x8 __attribute__((ext_vector_type(8)));
typedef float  f32x4  __attribute__((ext_vector_type(4)));

#define L_DIM 2048
#define N_DIM 8
#define E_DIM 2048
#define H_DIM 8192
#define T_DIM (L_DIM * N_DIM)   // 16384 tokens

// ---------------------------------------------------------------------------
__global__ __launch_bounds__(256) void cvt_f32_bf16(const float* __restrict__ in,
                                                    bf16_t* __restrict__ out,
                                                    int n4) {
    int stride = gridDim.x * blockDim.x;
    for (int i = blockIdx.x * blockDim.x + threadIdx.x; i < n4; i += stride) {
        float4 v = *(const float4*)(in + (size_t)i * 4);
        bf16x4 o;
        o[0] = (bf16_t)v.x; o[1] = (bf16_t)v.y;
        o[2] = (bf16_t)v.z; o[3] = (bf16_t)v.w;
        *(bf16x4*)(out + (size_t)i * 4) = o;
    }
}

// ---------------------------------------------------------------------------
__device__ __forceinline__ float fast_gelu(float x) {
    float x2 = x * x;
    float w  = x * __builtin_fmaf(0.1029456f, x2, 2.3022618f);
    w = fminf(w, 60.0f);
    float s = __builtin_amdgcn_exp2f(w);
    float r = __builtin_amdgcn_rcpf(s + 1.0f);
    return x * s * r;
}

// ---------------------------------------------------------------------------
// Persistent 256x256 GEMM, 2-barrier K-iter (R9 with phases merged pairwise).
// Each half-iter: [stage 2 half-tiles (opposite parity); ds_reads; counted
// vmcnt; BAR; lgkm0; 32-MFMA cluster]. Longer MFMA clusters hide the other
// wave's reads; half the barrier syncs vs R9 (which gave 47->53 MfmaUtil
// going 8->4 barriers).
// Safety (same invariants as R9):
//  - staging targets parity^1 only; A (0-32K) and B (32-64K) LDS regions are
//    disjoint, so intra-iter skew of any size is WAR-free; cross-iter skew
//    is blocked by the half-boundary barriers.
//  - vmcnt: at BAR1(u): outstanding = A1(u)[2] + B0,B1(u+1)[4] -> vmcnt(4)
//    drains A1(u) before half1's A-m4..7 reads. At BAR2(u): outstanding =
//    B0,B1,A0,A1(u+1)[8] -> vmcnt(2) drains B0,B1,A0(u+1) before half0(u+1)
//    reads them; A1(u+1) floats.
// Half0 reads rows 0..127 (=A0) + all B; half1 reads rows 128..255 (=A1).
// ---------------------------------------------------------------------------
template <bool GELU_OUT, int LG_NT, int LG_TN, int LG_NTILE, int KDIM, int NDIM>
__global__ __launch_bounds__(512, 2) void gemm256(const bf16_t* __restrict__ Am,
                                                  const bf16_t* __restrict__ Bm,
                                                  const float* __restrict__ bias,
                                                  void* __restrict__ Cout) {
    extern __shared__ char lds[];
    constexpr int NT    = 1 << LG_NT;      // K-tiles per output tile (KDIM/64)
    constexpr int ntile = 1 << LG_NTILE;   // output tiles per block
    constexpr int U     = ntile << LG_NT;  // total flat K-iterations

    const int tid  = threadIdx.x;
    const int lane = tid & 63;
    const int wid  = tid >> 6;
    const int wr   = wid >> 2;   // 0..1
    const int wc   = wid & 3;    // 0..3

    // XCD-aware bijective swizzle over the fixed 256-block grid (q = 32)
    const int wgb = (blockIdx.x & 7) * 32 + (blockIdx.x >> 3);
    const int g0  = wgb << LG_NTILE;

    // staging lane geometry: row_in_half = wid*8 + (lane>>3), phys slot = lane&7,
    // pre-swizzled logical col slot = (lane&7) ^ (row&7)  [row&7 == lane>>3]
    const int srow  = wid * 8 + (lane >> 3);
    const int scol8 = ((lane & 7) ^ (lane >> 3)) * 8;

    auto STAGE = [&](int isB, int half, int slot) {
        const int us  = (slot < U) ? slot : (U - 1);       // clamp tail (dummy)
        const int ti_ = us >> LG_NT;
        const int kt_ = us & (NT - 1);
        const int g_  = g0 + ti_;
        const size_t base_ = (size_t)(isB ? (g_ & ((1 << LG_TN) - 1)) : (g_ >> LG_TN)) << 8;
        // parity from UNCLAMPED slot -> dummies land in the dead buffer
        const unsigned reg_ = (unsigned)(((slot & 1) << 16) | (isB << 15) | (half << 14));
        const bf16_t* s0 = (isB ? Bm : Am)
                         + (base_ + (size_t)(half * 128 + srow)) * (size_t)KDIM
                         + (size_t)((kt_ << 6) + scol8);
        __builtin_amdgcn_global_load_lds(
            (const __attribute__((address_space(1))) void*)s0,
            (__attribute__((address_space(3))) void*)(lds + reg_ + (unsigned)(wid * 1024)),
            16, 0, 0);
        __builtin_amdgcn_global_load_lds(
            (const __attribute__((address_space(1))) void*)(s0 + (size_t)64 * KDIM),
            (__attribute__((address_space(3))) void*)(lds + reg_ + (unsigned)((8 + wid) * 1024)),
            16, 0, 0);
    };

    // M-frag m of wave wr -> tile row (m>>1)*64 + wr*32 + (m&1)*16
    auto ldsA = [&](unsigned bufo, int m, int kk) -> bf16x8 {
        const int row  = (m >> 1) * 64 + wr * 32 + (m & 1) * 16 + (lane & 15);
        const int slot = ((kk << 2) + (lane >> 4)) ^ (lane & 7);
        return *(const bf16x8*)(lds + bufo + row * 128 + slot * 16);
    };
    auto ldsB = [&](unsigned bufo, int n, int kk) -> bf16x8 {
        const int row  = wc * 64 + n * 16 + (lane & 15);
        const int slot = ((kk << 2) + (lane >> 4)) ^ (lane & 7);
        return *(const bf16x8*)(lds + bufo + 32768 + row * 128 + slot * 16);
    };

    f32x4 acc[8][4] = {};

    // Prologue: stage slot 0 completely, drain, publish.
    STAGE(1, 0, 0); STAGE(1, 1, 0); STAGE(0, 0, 0); STAGE(0, 1, 0);
    asm volatile("s_waitcnt vmcnt(0)" ::: "memory");
    __builtin_amdgcn_s_barrier();

    for (int ti = 0; ti < ntile; ++ti) {
        for (int t = 0; t < NT; ++t) {
            const int u = (ti << LG_NT) + t;
            const unsigned cur = (unsigned)(t & 1) * 65536u;   // == (u&1), NT even
            bf16x8 bf[4][2];
            bf16x8 af[4][2];

            // ======== half0: stage B0,B1(u+1); read B + A m0..3; MFMA m0..3 ====
            STAGE(1, 0, u + 1);
            STAGE(1, 1, u + 1);
#pragma unroll
            for (int n = 0; n < 4; ++n)
#pragma unroll
                for (int kk = 0; kk < 2; ++kk)
                    bf[n][kk] = ldsB(cur, n, kk);
#pragma unroll
            for (int mm = 0; mm < 4; ++mm)
#pragma unroll
                for (int kk = 0; kk < 2; ++kk)
                    af[mm][kk] = ldsA(cur, mm, kk);
            asm volatile("s_waitcnt vmcnt(4)" ::: "memory");   // A1(u) landed
            __builtin_amdgcn_s_barrier();
            asm volatile("s_waitcnt lgkmcnt(0)" ::: "memory");
            __builtin_amdgcn_s_setprio(1);
#pragma unroll
            for (int mm = 0; mm < 4; ++mm)
#pragma unroll
                for (int n = 0; n < 4; ++n)
#pragma unroll
                    for (int kk = 0; kk < 2; ++kk)
                        acc[mm][n] = __builtin_amdgcn_mfma_f32_16x16x32_bf16(
                            af[mm][kk], bf[n][kk], acc[mm][n], 0, 0, 0);
            __builtin_amdgcn_s_setprio(0);

            // ======== half1: stage A0,A1(u+1); read A m4..7; MFMA m4..7 ========
            STAGE(0, 0, u + 1);
            STAGE(0, 1, u + 1);
#pragma unroll
            for (int mm = 0; mm < 4; ++mm)
#pragma unroll
                for (int kk = 0; kk < 2; ++kk)
                    af[mm][kk] = ldsA(cur, 4 + mm, kk);
            asm volatile("s_waitcnt vmcnt(2)" ::: "memory");   // B0,B1,A0(u+1) landed
            __builtin_amdgcn_s_barrier();
            asm volatile("s_waitcnt lgkmcnt(0)" ::: "memory");
            __builtin_amdgcn_s_setprio(1);
#pragma unroll
            for (int mm = 0; mm < 4; ++mm)
#pragma unroll
                for (int n = 0; n < 4; ++n)
#pragma unroll
                    for (int kk = 0; kk < 2; ++kk)
                        acc[4 + mm][n] = __builtin_amdgcn_mfma_f32_16x16x32_bf16(
                            af[mm][kk], bf[n][kk], acc[4 + mm][n], 0, 0, 0);
            __builtin_amdgcn_s_setprio(0);
        }

        // ---- per-tile epilogue (reg-only, no LDS; between BAR2 and next BAR1) --
        const int g = g0 + ti;
        const size_t rowBase = (size_t)(g >> LG_TN) << 8;
        const size_t colBase = (size_t)(g & ((1 << LG_TN) - 1)) << 8;
        const int orow = (lane >> 4) * 4;
        const int ocol = lane & 15;
#pragma unroll
        for (int m = 0; m < 8; ++m) {
            const size_t rb = rowBase + (size_t)((m >> 1) * 64 + wr * 32 + (m & 1) * 16 + orow);
#pragma unroll
            for (int n = 0; n < 4; ++n) {
                const size_t col = colBase + (size_t)(wc * 64 + n * 16 + ocol);
                const float bv = bias[col];
#pragma unroll
                for (int j = 0; j < 4; ++j) {
                    float v = acc[m][n][j] + bv;
                    if constexpr (GELU_OUT) {
                        ((bf16_t*)Cout)[(rb + j) * (size_t)NDIM + col] = (bf16_t)fast_gelu(v);
                    } else {
                        ((float*)Cout)[(rb + j) * (size_t)NDIM + col] = v;
                    }
                }
                acc[m][n] = (f32x4){0.f, 0.f, 0.f, 0.f};
            }
        }
    }
    asm volatile("s_waitcnt vmcnt(0)" ::: "memory");   // drain tail dummy loads
}

// ---------------------------------------------------------------------------
extern "C" void kernel_launch(void* const* d_in, const int* in_sizes, int n_in,
                              void* d_out, int out_size, void* d_ws, size_t ws_size,
                              hipStream_t stream) {
    const float* x  = (const float*)d_in[0];  // [16384, 2048]
    const float* p1 = (const float*)d_in[1];  // [8192, 2048]
    const float* b1 = (const float*)d_in[2];  // [8192]
    const float* p2 = (const float*)d_in[3];  // [2048, 8192]
    const float* b2 = (const float*)d_in[4];  // [2048]
    // d_in[5] = gate_w, unused (routing is identity on the output)
    float* out = (float*)d_out;

    char* ws = (char*)d_ws;
    bf16_t* xb  = (bf16_t*)(ws);                          // 64 MB
    bf16_t* p1b = (bf16_t*)(ws + ((size_t)64 << 20));     // 32 MB
    bf16_t* p2b = (bf16_t*)(ws + ((size_t)96 << 20));     // 32 MB
    bf16_t* h   = (bf16_t*)(ws + ((size_t)128 << 20));    // 256 MB

    // GEMM1: [T,E] x [H,E]^T -> h.  2048 tiles = 256 blocks x 8 tiles.
    auto g1 = gemm256<true, 5, 5, 3, E_DIM, H_DIM>;
    // GEMM2: [T,H] x [E,H]^T -> out. 512 tiles = 256 blocks x 2 tiles.
    auto g2 = gemm256<false, 7, 3, 1, H_DIM, E_DIM>;

    (void)hipFuncSetAttribute((const void*)g1,
                              hipFuncAttributeMaxDynamicSharedMemorySize, 131072);
    (void)hipFuncSetAttribute((const void*)g2,
                              hipFuncAttributeMaxDynamicSharedMemorySize, 131072);

    cvt_f32_bf16<<<2048, 256, 0, stream>>>(x,  xb,  (T_DIM * E_DIM) / 4);
    cvt_f32_bf16<<<1024, 256, 0, stream>>>(p1, p1b, (H_DIM * E_DIM) / 4);
    cvt_f32_bf16<<<1024, 256, 0, stream>>>(p2, p2b, (E_DIM * H_DIM) / 4);

    g1<<<256, 512, 131072, stream>>>(xb, p1b, b1, (void*)h);
    g2<<<256, 512, 131072, stream>>>(h, p2b, b2, (void*)out);
}